// Round 5
// baseline (1592.777 us; speedup 1.0000x reference)
//
#include <hip/hip_runtime.h>

// GCN 2-layer, bucket-CSR build + bucket-block LDS-scatter gather.
//   out[c] = dinv[c] * ( h_s[c] + sum_{e: col=c} h_s[row_e] ) + b,  h_s=(X@W)*dinv
// R14: deleted k_bucket_sort. k_bin emits per-bucket entry regions (unsorted
// within bucket) + per-node degrees (global atomicAdd in hist pass). Gather is
// now one block per 128-node bucket: 32KB LDS fp32 acc[ch][node] (ch-major so
// random-node ds_add spreads banks), init = self-loop rows, then stream the
// bucket's entries (1/lane, 8x dwordx4 row load, 64x ds_add_f32), epilogue
// scales by rsqrt(deg+1), +bias, relu/pack. Removes a full 25MB entry pass,
// one launch, and all per-node serial loops. R13's channel slicing reverted
// (55MB compulsory over-fetch from 4x duplication; 42->67us regression).
// Messages bf16, accum fp32. Requires N < 2^17. Int inputs arrive as int32.

#define BKT_SH 7            // 128 nodes per bucket
#define BKT_CAP 4096        // region per bucket (counts ~2046 +- 45; huge margin)
#define CHUNK 6144          // edges per k_bin block
#define BM 128
#define BK 32

__device__ __forceinline__ unsigned short f2bf(float f) {
    unsigned u = __builtin_bit_cast(unsigned, f);
    u = (u + 0x7FFF + ((u >> 16) & 1)) >> 16;  // RNE
    return (unsigned short)u;
}
__device__ __forceinline__ float bflo(unsigned u) {  // low bf16 of packed pair
    return __builtin_bit_cast(float, u << 16);
}
__device__ __forceinline__ float bfhi(unsigned u) {  // high bf16 of packed pair
    return __builtin_bit_cast(float, u & 0xFFFF0000u);
}

__global__ __launch_bounds__(256) void k_zero_i(int* __restrict__ p, int n) {
    int i = blockIdx.x * 256 + threadIdx.x;
    if (i < n) p[i] = 0;
}

// (A) block-chunked binning: LDS hist -> LDS scan -> one count-reservation
// atomic per (block,bucket) -> LDS sort by bucket -> run-coalesced writes into
// fixed bucket region [bkt*CAP, (bkt+1)*CAP). cursor zero-init; ends = counts.
// Also counts per-node in-degree via global atomics (deg zero-init).
__global__ __launch_bounds__(256) void k_bin(const int* __restrict__ row,
                                             const int* __restrict__ col,
                                             int* __restrict__ cursor,
                                             int* __restrict__ deg,
                                             unsigned* __restrict__ bentries,
                                             int E) {
    __shared__ unsigned sorted[CHUNK];        // 24 KB packed entries, bucket order
    __shared__ unsigned short bof[CHUNK];     // 12 KB bucket of sorted[i]
    __shared__ int hist[1024];
    __shared__ int ex0[1024];
    __shared__ int cur[1024];
    __shared__ int gbase[1024];
    __shared__ int tsum[256];
    int b = blockIdx.x, t = threadIdx.x;
    int s0 = b * CHUNK;
    int cnt = E - s0; if (cnt > CHUNK) cnt = CHUNK;

    for (int i = t; i < 1024; i += 256) hist[i] = 0;
    __syncthreads();
    // pass 1: histogram (+ per-node degree, fire-and-forget global atomics)
    for (int i = t; i < cnt; i += 256) {
        int c = col[s0 + i];
        atomicAdd(&hist[c >> BKT_SH], 1);
        atomicAdd(&deg[c], 1);
    }
    __syncthreads();
    // scan 1024 bins: thread t owns bins [4t, 4t+4)
    {
        int b0 = hist[4 * t], b1 = hist[4 * t + 1], b2 = hist[4 * t + 2], b3 = hist[4 * t + 3];
        int tot = b0 + b1 + b2 + b3;
        tsum[t] = tot;
        __syncthreads();
#pragma unroll
        for (int d = 1; d < 256; d <<= 1) {
            int x = (t >= d) ? tsum[t - d] : 0;
            __syncthreads();
            tsum[t] += (t >= d) ? x : 0;
            __syncthreads();
        }
        int ex = tsum[t] - tot;  // exclusive across thread groups
        ex0[4 * t] = ex;
        ex0[4 * t + 1] = ex + b0;
        ex0[4 * t + 2] = ex + b0 + b1;
        ex0[4 * t + 3] = ex + b0 + b1 + b2;
        cur[4 * t] = ex0[4 * t];
        cur[4 * t + 1] = ex0[4 * t + 1];
        cur[4 * t + 2] = ex0[4 * t + 2];
        cur[4 * t + 3] = ex0[4 * t + 3];
    }
    __syncthreads();
    // reserve: one atomic per non-empty (block,bucket); region base is fixed
    for (int i = t; i < 1024; i += 256)
        if (hist[i] > 0) gbase[i] = i * BKT_CAP + atomicAdd(&cursor[i], hist[i]);
    // pass 2: LDS sort by bucket (order within bucket irrelevant)
    for (int i = t; i < cnt; i += 256) {
        int c = col[s0 + i], r = row[s0 + i];
        int bkt = c >> BKT_SH;
        int p = atomicAdd(&cur[bkt], 1);
        sorted[p] = ((unsigned)(c & ((1 << BKT_SH) - 1)) << 17) | (unsigned)r;
        bof[p] = (unsigned short)bkt;
    }
    __syncthreads();
    // pass 3: run-coalesced global writes (guard against region overflow)
    for (int i = t; i < cnt; i += 256) {
        int bkt = bof[i];
        int pos = gbase[bkt] + (i - ex0[bkt]);
        if (pos < (bkt + 1) * BKT_CAP) bentries[pos] = sorted[i];
    }
}

// Tiled GEMM + row scale, fp32 input, bf16 output (natural [node][64] layout).
// Row scale dinv = rsqrt(deg+1) computed inline from the degree array.
__global__ __launch_bounds__(256) void k_gemm_f32in(
    const float* __restrict__ X, const float* __restrict__ W,
    const int* __restrict__ deg, unsigned short* __restrict__ outb,
    int N, int K) {
    __shared__ float Xs[BK][BM + 4];
    __shared__ float Ws[BK][64];
    int t = threadIdx.x;
    int bm = blockIdx.x * BM;
    int tm = t >> 4, tn = t & 15;

    float acc[8][4];
#pragma unroll
    for (int i = 0; i < 8; ++i)
#pragma unroll
        for (int j = 0; j < 4; ++j) acc[i][j] = 0.f;

    for (int kb = 0; kb < K; kb += BK) {
#pragma unroll
        for (int it = 0; it < 4; ++it) {
            int r = (t >> 3) + 32 * it;       // 0..127
            int grow = bm + r;
            int k4 = t & 7;                   // float4 index within BK
            float4 v = make_float4(0.f, 0.f, 0.f, 0.f);
            if (grow < N) v = *(const float4*)(X + (size_t)grow * K + kb + k4 * 4);
            Xs[k4 * 4 + 0][r] = v.x;
            Xs[k4 * 4 + 1][r] = v.y;
            Xs[k4 * 4 + 2][r] = v.z;
            Xs[k4 * 4 + 3][r] = v.w;
        }
#pragma unroll
        for (int it = 0; it < 2; ++it) {
            int idx = t + 256 * it;           // 0..511 float4s
            ((float4*)Ws)[idx] = ((const float4*)(W + (size_t)kb * 64))[idx];
        }
        __syncthreads();
#pragma unroll
        for (int k = 0; k < BK; ++k) {
            float4 xa = *(const float4*)&Xs[k][tm * 8];
            float4 xb = *(const float4*)&Xs[k][tm * 8 + 4];
            float4 w = *(const float4*)&Ws[k][tn * 4];
            float xs[8] = {xa.x, xa.y, xa.z, xa.w, xb.x, xb.y, xb.z, xb.w};
#pragma unroll
            for (int i = 0; i < 8; ++i) {
                acc[i][0] = fmaf(xs[i], w.x, acc[i][0]);
                acc[i][1] = fmaf(xs[i], w.y, acc[i][1]);
                acc[i][2] = fmaf(xs[i], w.z, acc[i][2]);
                acc[i][3] = fmaf(xs[i], w.w, acc[i][3]);
            }
        }
        __syncthreads();
    }
#pragma unroll
    for (int i = 0; i < 8; ++i) {
        int grow = bm + tm * 8 + i;
        if (grow < N) {
            float s = rsqrtf((float)deg[grow] + 1.0f);
            ushort4 v;
            v.x = f2bf(acc[i][0] * s);
            v.y = f2bf(acc[i][1] * s);
            v.z = f2bf(acc[i][2] * s);
            v.w = f2bf(acc[i][3] * s);
            *(ushort4*)(outb + (size_t)grow * 64 + tn * 4) = v;
        }
    }
}

// Tiled GEMM + row scale, bf16 input (natural layout), bf16 output.
__global__ __launch_bounds__(256) void k_gemm_bf16in(
    const unsigned short* __restrict__ Xb, const float* __restrict__ W,
    const int* __restrict__ deg, unsigned short* __restrict__ outb,
    int N, int K) {
    __shared__ float Xs[BK][BM + 4];
    __shared__ float Ws[BK][64];
    int t = threadIdx.x;
    int bm = blockIdx.x * BM;
    int tm = t >> 4, tn = t & 15;

    float acc[8][4];
#pragma unroll
    for (int i = 0; i < 8; ++i)
#pragma unroll
        for (int j = 0; j < 4; ++j) acc[i][j] = 0.f;

    for (int kb = 0; kb < K; kb += BK) {
        // 128 rows x 32 k bf16 = 512 uint4 (8 bf16 each); 2 per thread
#pragma unroll
        for (int it = 0; it < 2; ++it) {
            int idx = t * 2 + it;             // 0..511
            int r = idx >> 2;                 // 0..127
            int q = idx & 3;                  // 16B chunk: k = q*8..q*8+8
            int grow = bm + r;
            uint4 v = make_uint4(0u, 0u, 0u, 0u);
            if (grow < N) v = *(const uint4*)(Xb + (size_t)grow * K + kb + q * 8);
            int k0 = q * 8;
            Xs[k0 + 0][r] = bflo(v.x); Xs[k0 + 1][r] = bfhi(v.x);
            Xs[k0 + 2][r] = bflo(v.y); Xs[k0 + 3][r] = bfhi(v.y);
            Xs[k0 + 4][r] = bflo(v.z); Xs[k0 + 5][r] = bfhi(v.z);
            Xs[k0 + 6][r] = bflo(v.w); Xs[k0 + 7][r] = bfhi(v.w);
        }
#pragma unroll
        for (int it = 0; it < 2; ++it) {
            int idx = t + 256 * it;           // 0..511 float4s
            ((float4*)Ws)[idx] = ((const float4*)(W + (size_t)kb * 64))[idx];
        }
        __syncthreads();
#pragma unroll
        for (int k = 0; k < BK; ++k) {
            float4 xa = *(const float4*)&Xs[k][tm * 8];
            float4 xb = *(const float4*)&Xs[k][tm * 8 + 4];
            float4 w = *(const float4*)&Ws[k][tn * 4];
            float xs[8] = {xa.x, xa.y, xa.z, xa.w, xb.x, xb.y, xb.z, xb.w};
#pragma unroll
            for (int i = 0; i < 8; ++i) {
                acc[i][0] = fmaf(xs[i], w.x, acc[i][0]);
                acc[i][1] = fmaf(xs[i], w.y, acc[i][1]);
                acc[i][2] = fmaf(xs[i], w.z, acc[i][2]);
                acc[i][3] = fmaf(xs[i], w.w, acc[i][3]);
            }
        }
        __syncthreads();
    }
#pragma unroll
    for (int i = 0; i < 8; ++i) {
        int grow = bm + tm * 8 + i;
        if (grow < N) {
            float s = rsqrtf((float)deg[grow] + 1.0f);
            ushort4 v;
            v.x = f2bf(acc[i][0] * s);
            v.y = f2bf(acc[i][1] * s);
            v.z = f2bf(acc[i][2] * s);
            v.w = f2bf(acc[i][3] * s);
            *(ushort4*)(outb + (size_t)grow * 64 + tn * 4) = v;
        }
    }
}

// (C) bucket-block LDS-scatter gather. One block per 128-node bucket.
// acc[ch][local] fp32 in LDS (ch-major: ds_add bank = local%32, random ->
// spread). init = self-loop rows. Stream unsorted entries, 1/lane: load the
// 128B source row (8x dwordx4, MLP), 64x atomicAdd into acc column c.
// Epilogue: *rsqrt(deg+1) + bias (+relu/bf16-pack for mode 1).
__global__ __launch_bounds__(256) void k_gather(
    const uint4* __restrict__ srcq, const unsigned* __restrict__ bentries,
    const int* __restrict__ bcnt, const int* __restrict__ deg,
    const float* __restrict__ bias,
    float* __restrict__ dstf, uint4* __restrict__ dstq, int N, int mode) {
    __shared__ float acc[64][128];  // 32 KB
    int b = blockIdx.x, t = threadIdx.x;
    int base = b * BKT_CAP;
    int node0 = b << BKT_SH;
    int cnt = bcnt[b];
    if (cnt > BKT_CAP) cnt = BKT_CAP;  // safety clamp (never expected)

    // init with self-loop rows: 128 nodes x 8 uint4 = 1024; 4 per thread
#pragma unroll
    for (int it = 0; it < 4; ++it) {
        int idx = t + 256 * it;   // 0..1023
        int c = idx >> 3, j = idx & 7;
        int node = node0 + c;
        uint4 v = make_uint4(0u, 0u, 0u, 0u);
        if (node < N) v = srcq[(size_t)node * 8 + j];
        int ch = j * 8;
        acc[ch + 0][c] = bflo(v.x); acc[ch + 1][c] = bfhi(v.x);
        acc[ch + 2][c] = bflo(v.y); acc[ch + 3][c] = bfhi(v.y);
        acc[ch + 4][c] = bflo(v.z); acc[ch + 5][c] = bfhi(v.z);
        acc[ch + 6][c] = bflo(v.w); acc[ch + 7][c] = bfhi(v.w);
    }
    __syncthreads();

    // stream entries: one per lane
    for (int i = t; i < cnt; i += 256) {
        unsigned en = bentries[base + i];
        int c = (int)(en >> 17);
        int r = (int)(en & 0x1FFFFu);
        const uint4* p = srcq + (size_t)r * 8;
        uint4 v0 = p[0], v1 = p[1], v2 = p[2], v3 = p[3];
        uint4 v4 = p[4], v5 = p[5], v6 = p[6], v7 = p[7];
        uint4 vv[8] = {v0, v1, v2, v3, v4, v5, v6, v7};
#pragma unroll
        for (int j = 0; j < 8; ++j) {
            int ch = j * 8;
            atomicAdd(&acc[ch + 0][c], bflo(vv[j].x));
            atomicAdd(&acc[ch + 1][c], bfhi(vv[j].x));
            atomicAdd(&acc[ch + 2][c], bflo(vv[j].y));
            atomicAdd(&acc[ch + 3][c], bfhi(vv[j].y));
            atomicAdd(&acc[ch + 4][c], bflo(vv[j].z));
            atomicAdd(&acc[ch + 5][c], bfhi(vv[j].z));
            atomicAdd(&acc[ch + 6][c], bflo(vv[j].w));
            atomicAdd(&acc[ch + 7][c], bfhi(vv[j].w));
        }
    }
    __syncthreads();

    // epilogue: thread handles node c = t>>1, channel half l = t&1 (32 ch)
    int c = t >> 1, l = t & 1;
    int node = node0 + c;
    if (node >= N) return;
    float dv = rsqrtf((float)deg[node] + 1.0f);
    if (mode) {  // relu + bf16 pack, natural [node][64] layout
#pragma unroll
        for (int q = 0; q < 4; ++q) {
            int ch0 = l * 32 + q * 8;
            float4 b0 = *(const float4*)(bias + ch0);
            float4 b1 = *(const float4*)(bias + ch0 + 4);
            float x0 = fmaxf(acc[ch0 + 0][c] * dv + b0.x, 0.f);
            float x1 = fmaxf(acc[ch0 + 1][c] * dv + b0.y, 0.f);
            float x2 = fmaxf(acc[ch0 + 2][c] * dv + b0.z, 0.f);
            float x3 = fmaxf(acc[ch0 + 3][c] * dv + b0.w, 0.f);
            float x4 = fmaxf(acc[ch0 + 4][c] * dv + b1.x, 0.f);
            float x5 = fmaxf(acc[ch0 + 5][c] * dv + b1.y, 0.f);
            float x6 = fmaxf(acc[ch0 + 6][c] * dv + b1.z, 0.f);
            float x7 = fmaxf(acc[ch0 + 7][c] * dv + b1.w, 0.f);
            uint4 o;
            o.x = (unsigned)f2bf(x0) | ((unsigned)f2bf(x1) << 16);
            o.y = (unsigned)f2bf(x2) | ((unsigned)f2bf(x3) << 16);
            o.z = (unsigned)f2bf(x4) | ((unsigned)f2bf(x5) << 16);
            o.w = (unsigned)f2bf(x6) | ((unsigned)f2bf(x7) << 16);
            dstq[(size_t)node * 8 + l * 4 + q] = o;
        }
    } else {     // fp32 final out, natural [node][64] layout
#pragma unroll
        for (int q = 0; q < 4; ++q) {
            int ch0 = l * 32 + q * 8;
            float4 b0 = *(const float4*)(bias + ch0);
            float4 b1 = *(const float4*)(bias + ch0 + 4);
            float4 o0, o1;
            o0.x = acc[ch0 + 0][c] * dv + b0.x;
            o0.y = acc[ch0 + 1][c] * dv + b0.y;
            o0.z = acc[ch0 + 2][c] * dv + b0.z;
            o0.w = acc[ch0 + 3][c] * dv + b0.w;
            o1.x = acc[ch0 + 4][c] * dv + b1.x;
            o1.y = acc[ch0 + 5][c] * dv + b1.y;
            o1.z = acc[ch0 + 6][c] * dv + b1.z;
            o1.w = acc[ch0 + 7][c] * dv + b1.w;
            *(float4*)(dstf + (size_t)node * 64 + ch0) = o0;
            *(float4*)(dstf + (size_t)node * 64 + ch0 + 4) = o1;
        }
    }
}

extern "C" void kernel_launch(void* const* d_in, const int* in_sizes, int n_in,
                              void* d_out, int out_size, void* d_ws, size_t ws_size,
                              hipStream_t stream) {
    const float* x = (const float*)d_in[0];
    const int* ei = (const int*)d_in[1];  // int32 per harness contract, [2, E]
    const float* W1 = (const float*)d_in[2];
    const float* b1 = (const float*)d_in[3];
    const float* W2 = (const float*)d_in[4];
    const float* b2 = (const float*)d_in[5];

    int N = in_sizes[0] / 128;  // 100000
    int E = in_sizes[1] / 2;    // 1600000
    const int* row = ei;
    const int* col = ei + E;
    int nb = (N + (1 << BKT_SH) - 1) >> BKT_SH;  // 782 buckets

    char* ws = (char*)d_ws;
    int* cursor = (int*)ws;                          // nb ints @ 0
    int* deg = (int*)(ws + (1 << 16));               // N ints @ 64 KB
    unsigned* bentries = (unsigned*)(ws + (2 << 20));    // nb*CAP u32 @ 2 MB (12.8 MB)
    unsigned short* Ab = (unsigned short*)(ws + (15 << 20));  // N*64 bf16 @ 15 MB
    unsigned short* Hb = (unsigned short*)d_out;     // bf16 h2 scratch in d_out
    float* OUTF = (float*)d_out;                     // final fp32 output

    int nzero = (1 << 14) + N;             // cursor region (64KB) + deg, as ints
    int gemmblk = (N + BM - 1) / BM;       // 782
    int binblk = (E + CHUNK - 1) / CHUNK;  // 261

    // --- CSR build (padded buckets, unsorted within bucket; + degrees) ---
    k_zero_i<<<(nzero + 255) / 256, 256, 0, stream>>>(cursor, nzero);
    k_bin<<<binblk, 256, 0, stream>>>(row, col, cursor, deg, bentries, E);

    // Layer 1: Ab = bf16((X@W1)*dinv); Hb = bf16(relu(gather(Ab)*dinv + b1))
    k_gemm_f32in<<<gemmblk, 256, 0, stream>>>(x, W1, deg, Ab, N, 128);
    k_gather<<<nb, 256, 0, stream>>>((const uint4*)Ab, bentries, cursor, deg,
                                     b1, nullptr, (uint4*)Hb, N, 1);

    // Layer 2: Ab = bf16((Hb@W2)*dinv); d_out = gather(Ab)*dinv + b2 (fp32)
    k_gemm_bf16in<<<gemmblk, 256, 0, stream>>>(Hb, W2, deg, Ab, N, 64);
    k_gather<<<nb, 256, 0, stream>>>((const uint4*)Ab, bentries, cursor, deg,
                                     b2, OUTF, nullptr, N, 0);
}

// Round 6
// 370.842 us; speedup vs baseline: 4.2950x; 4.2950x over previous
//
#include <hip/hip_runtime.h>
#include <hip/hip_cooperative_groups.h>

namespace cg = cooperative_groups;

// GCN 2-layer, single cooperative mega-kernel.
//   out[c] = dinv[c] * ( h_s[c] + sum_{e: col=c} h_s[row_e] ) + b,  h_s=(X@W)*dinv
// R15: R12's verified 7-kernel pipeline fused into ONE hipLaunchCooperativeKernel
// with grid.sync() between phases. Triangulation across R11/R12/R13b runs:
// gathers ~38us each, gemms ~21, bin/bsort <=42 -> ~80-110us of R12's 250 was
// inter-launch overhead (~12-15us/boundary). Phases grid-stride; one 35KB LDS
// buffer reused (bin 35K / bsort 17.5K / gemm 24.5K). CHUNK 6144->3072 gives
// bin 2 blocks/CU (was 1). Non-coop 7-launch fallback if coop unavailable.
// R14 post-mortem: LDS-atomic scatter gather = 689us (1.6M bank conflicts,
// 102M serialized ds_add) -- sorted per-node lists + sequential gather stays.
// Messages bf16, accum fp32. Requires N < 2^17. Int inputs arrive as int32.

#define BKT_SH 7            // 128 nodes per bucket
#define BKT_CAP 4096        // region per bucket (counts ~2046 +- 45; huge margin)
#define CHUNK 3072          // edges per bin chunk (521 chunks -> 2 blocks/CU)
#define BM 128
#define BK 32
#define NTH 256
#define SMEM_BYTES 35840

__device__ __forceinline__ unsigned short f2bf(float f) {
    unsigned u = __builtin_bit_cast(unsigned, f);
    u = (u + 0x7FFF + ((u >> 16) & 1)) >> 16;  // RNE
    return (unsigned short)u;
}
__device__ __forceinline__ float bflo(unsigned u) {  // low bf16 of packed pair
    return __builtin_bit_cast(float, u << 16);
}
__device__ __forceinline__ float bfhi(unsigned u) {  // high bf16 of packed pair
    return __builtin_bit_cast(float, u & 0xFFFF0000u);
}

struct GcnParams {
    const float* x;
    const int* row;
    const int* col;
    const float* W1;
    const float* b1;
    const float* W2;
    const float* b2;
    int* cursor;
    int* start;
    int* cntarr;
    float* dinv;
    unsigned* bentries;
    unsigned short* Ab;
    unsigned short* Hb;   // bf16 h2 scratch (in d_out)
    float* outf;          // final fp32 out (d_out)
    int N, E, nb, nchunks, gemmblk;
};

// ---------------- phase: zero cursor ----------------
__device__ void ph_zero(int* p, int n, int gtid, int gsz) {
    for (int i = gtid; i < n; i += gsz) p[i] = 0;
}

// ---------------- phase: block-chunked binning ----------------
// LDS hist -> scan -> one reservation atomic per (chunk,bucket) -> LDS sort by
// bucket -> run-coalesced writes into fixed region [bkt*CAP, (bkt+1)*CAP).
__device__ void ph_bin(char* smem, int bId, int nB,
                       const int* __restrict__ row, const int* __restrict__ col,
                       int* __restrict__ cursor, unsigned* __restrict__ bentries,
                       int E, int nchunks) {
    unsigned* sorted = (unsigned*)(smem);                 // 12288
    unsigned short* bof = (unsigned short*)(smem + 12288); // 6144
    int* hist = (int*)(smem + 18432);                     // 4096
    int* ex0 = (int*)(smem + 22528);
    int* cur = (int*)(smem + 26624);
    int* gbase = (int*)(smem + 30720);
    int* tsum = (int*)(smem + 34816);                     // 1024
    int t = threadIdx.x;

    for (int chn = bId; chn < nchunks; chn += nB) {
        int s0 = chn * CHUNK;
        int cnt = E - s0; if (cnt > CHUNK) cnt = CHUNK;

        for (int i = t; i < 1024; i += NTH) hist[i] = 0;
        __syncthreads();
        // pass 1: histogram
        for (int i = t; i < cnt; i += NTH)
            atomicAdd(&hist[col[s0 + i] >> BKT_SH], 1);
        __syncthreads();
        // scan 1024 bins: thread t owns bins [4t, 4t+4)
        {
            int b0 = hist[4 * t], b1 = hist[4 * t + 1];
            int b2 = hist[4 * t + 2], b3 = hist[4 * t + 3];
            int tot = b0 + b1 + b2 + b3;
            tsum[t] = tot;
            __syncthreads();
#pragma unroll
            for (int d = 1; d < 256; d <<= 1) {
                int x = (t >= d) ? tsum[t - d] : 0;
                __syncthreads();
                tsum[t] += (t >= d) ? x : 0;
                __syncthreads();
            }
            int ex = tsum[t] - tot;
            ex0[4 * t] = ex;
            ex0[4 * t + 1] = ex + b0;
            ex0[4 * t + 2] = ex + b0 + b1;
            ex0[4 * t + 3] = ex + b0 + b1 + b2;
            cur[4 * t] = ex0[4 * t];
            cur[4 * t + 1] = ex0[4 * t + 1];
            cur[4 * t + 2] = ex0[4 * t + 2];
            cur[4 * t + 3] = ex0[4 * t + 3];
        }
        __syncthreads();
        // reserve region space: one global atomic per non-empty bucket
        for (int i = t; i < 1024; i += NTH)
            if (hist[i] > 0) gbase[i] = i * BKT_CAP + atomicAdd(&cursor[i], hist[i]);
        // pass 2: LDS sort by bucket
        for (int i = t; i < cnt; i += NTH) {
            int c = col[s0 + i], r = row[s0 + i];
            int bkt = c >> BKT_SH;
            int p = atomicAdd(&cur[bkt], 1);
            sorted[p] = ((unsigned)(c & ((1 << BKT_SH) - 1)) << 17) | (unsigned)r;
            bof[p] = (unsigned short)bkt;
        }
        __syncthreads();
        // pass 3: run-coalesced global writes
        for (int i = t; i < cnt; i += NTH) {
            int bkt = bof[i];
            int pos = gbase[bkt] + (i - ex0[bkt]);
            if (pos < (bkt + 1) * BKT_CAP) bentries[pos] = sorted[i];
        }
        __syncthreads();
    }
}

// ---------------- phase: per-bucket counting sort ----------------
__device__ void ph_bsort(char* smem, int bId, int nB,
                         unsigned* __restrict__ bentries, const int* __restrict__ cursor,
                         int* __restrict__ start, int* __restrict__ cntarr,
                         float* __restrict__ dinv, int N, int nb) {
    int* hist = (int*)(smem);            // 512
    int* incl = (int*)(smem + 512);
    int* cur = (int*)(smem + 1024);
    int* rows = (int*)(smem + 1536);     // 16384
    int t = threadIdx.x;

    for (int b = bId; b < nb; b += nB) {
        int base = b * BKT_CAP;
        int cnt = cursor[b];
        if (cnt > BKT_CAP) cnt = BKT_CAP;

        if (t < 128) hist[t] = 0;
        __syncthreads();
        for (int i = t; i < cnt; i += NTH)
            atomicAdd(&hist[bentries[base + i] >> 17], 1);
        __syncthreads();
        if (t < 128) incl[t] = hist[t];
        __syncthreads();
#pragma unroll
        for (int d = 1; d < 128; d <<= 1) {
            int x = (t < 128 && t >= d) ? incl[t - d] : 0;
            __syncthreads();
            if (t < 128 && t >= d) incl[t] += x;
            __syncthreads();
        }
        if (t < 128) {
            int ex = incl[t] - hist[t];
            int node = (b << BKT_SH) + t;
            if (node < N) {
                start[node] = base + ex;
                cntarr[node] = hist[t];
                dinv[node] = rsqrtf((float)hist[t] + 1.0f);  // +1 self loop
            }
            cur[t] = ex;
        }
        __syncthreads();
        for (int i = t; i < cnt; i += NTH) {
            unsigned en = bentries[base + i];
            int p = atomicAdd(&cur[en >> 17], 1);
            rows[p] = (int)(en & 0x1FFFF);
        }
        __syncthreads();
        for (int i = t; i < cnt; i += NTH) bentries[base + i] = (unsigned)rows[i];
        __syncthreads();
    }
}

// ---------------- phase: GEMM (fp32 in), bf16 out, *dinv ----------------
__device__ void ph_gemm_f32(char* smem, int bId, int nB,
                            const float* __restrict__ X, const float* __restrict__ W,
                            const float* __restrict__ dinv,
                            unsigned short* __restrict__ outb,
                            int N, int K, int gemmblk) {
    float (*Xs)[BM + 4] = (float(*)[BM + 4])(smem);       // 16896
    float (*Ws)[64] = (float(*)[64])(smem + 16896);       // 8192
    int t = threadIdx.x;
    int tm = t >> 4, tn = t & 15;

    for (int tile = bId; tile < gemmblk; tile += nB) {
        int bm = tile * BM;
        float acc[8][4];
#pragma unroll
        for (int i = 0; i < 8; ++i)
#pragma unroll
            for (int j = 0; j < 4; ++j) acc[i][j] = 0.f;

        for (int kb = 0; kb < K; kb += BK) {
#pragma unroll
            for (int it = 0; it < 4; ++it) {
                int r = (t >> 3) + 32 * it;
                int grow = bm + r;
                int k4 = t & 7;
                float4 v = make_float4(0.f, 0.f, 0.f, 0.f);
                if (grow < N) v = *(const float4*)(X + (size_t)grow * K + kb + k4 * 4);
                Xs[k4 * 4 + 0][r] = v.x;
                Xs[k4 * 4 + 1][r] = v.y;
                Xs[k4 * 4 + 2][r] = v.z;
                Xs[k4 * 4 + 3][r] = v.w;
            }
#pragma unroll
            for (int it = 0; it < 2; ++it) {
                int idx = t + NTH * it;
                ((float4*)Ws)[idx] = ((const float4*)(W + (size_t)kb * 64))[idx];
            }
            __syncthreads();
#pragma unroll
            for (int k = 0; k < BK; ++k) {
                float4 xa = *(const float4*)&Xs[k][tm * 8];
                float4 xb = *(const float4*)&Xs[k][tm * 8 + 4];
                float4 w = *(const float4*)&Ws[k][tn * 4];
                float xs[8] = {xa.x, xa.y, xa.z, xa.w, xb.x, xb.y, xb.z, xb.w};
#pragma unroll
                for (int i = 0; i < 8; ++i) {
                    acc[i][0] = fmaf(xs[i], w.x, acc[i][0]);
                    acc[i][1] = fmaf(xs[i], w.y, acc[i][1]);
                    acc[i][2] = fmaf(xs[i], w.z, acc[i][2]);
                    acc[i][3] = fmaf(xs[i], w.w, acc[i][3]);
                }
            }
            __syncthreads();
        }
#pragma unroll
        for (int i = 0; i < 8; ++i) {
            int grow = bm + tm * 8 + i;
            if (grow < N) {
                float s = dinv[grow];
                ushort4 v;
                v.x = f2bf(acc[i][0] * s);
                v.y = f2bf(acc[i][1] * s);
                v.z = f2bf(acc[i][2] * s);
                v.w = f2bf(acc[i][3] * s);
                *(ushort4*)(outb + (size_t)grow * 64 + tn * 4) = v;
            }
        }
        __syncthreads();
    }
}

// ---------------- phase: GEMM (bf16 in), bf16 out, *dinv ----------------
__device__ void ph_gemm_bf16(char* smem, int bId, int nB,
                             const unsigned short* __restrict__ Xb,
                             const float* __restrict__ W,
                             const float* __restrict__ dinv,
                             unsigned short* __restrict__ outb,
                             int N, int K, int gemmblk) {
    float (*Xs)[BM + 4] = (float(*)[BM + 4])(smem);
    float (*Ws)[64] = (float(*)[64])(smem + 16896);
    int t = threadIdx.x;
    int tm = t >> 4, tn = t & 15;

    for (int tile = bId; tile < gemmblk; tile += nB) {
        int bm = tile * BM;
        float acc[8][4];
#pragma unroll
        for (int i = 0; i < 8; ++i)
#pragma unroll
            for (int j = 0; j < 4; ++j) acc[i][j] = 0.f;

        for (int kb = 0; kb < K; kb += BK) {
#pragma unroll
            for (int it = 0; it < 2; ++it) {
                int idx = t * 2 + it;
                int r = idx >> 2;
                int q = idx & 3;
                int grow = bm + r;
                uint4 v = make_uint4(0u, 0u, 0u, 0u);
                if (grow < N) v = *(const uint4*)(Xb + (size_t)grow * K + kb + q * 8);
                int k0 = q * 8;
                Xs[k0 + 0][r] = bflo(v.x); Xs[k0 + 1][r] = bfhi(v.x);
                Xs[k0 + 2][r] = bflo(v.y); Xs[k0 + 3][r] = bfhi(v.y);
                Xs[k0 + 4][r] = bflo(v.z); Xs[k0 + 5][r] = bfhi(v.z);
                Xs[k0 + 6][r] = bflo(v.w); Xs[k0 + 7][r] = bfhi(v.w);
            }
#pragma unroll
            for (int it = 0; it < 2; ++it) {
                int idx = t + NTH * it;
                ((float4*)Ws)[idx] = ((const float4*)(W + (size_t)kb * 64))[idx];
            }
            __syncthreads();
#pragma unroll
            for (int k = 0; k < BK; ++k) {
                float4 xa = *(const float4*)&Xs[k][tm * 8];
                float4 xb = *(const float4*)&Xs[k][tm * 8 + 4];
                float4 w = *(const float4*)&Ws[k][tn * 4];
                float xs[8] = {xa.x, xa.y, xa.z, xa.w, xb.x, xb.y, xb.z, xb.w};
#pragma unroll
                for (int i = 0; i < 8; ++i) {
                    acc[i][0] = fmaf(xs[i], w.x, acc[i][0]);
                    acc[i][1] = fmaf(xs[i], w.y, acc[i][1]);
                    acc[i][2] = fmaf(xs[i], w.z, acc[i][2]);
                    acc[i][3] = fmaf(xs[i], w.w, acc[i][3]);
                }
            }
            __syncthreads();
        }
#pragma unroll
        for (int i = 0; i < 8; ++i) {
            int grow = bm + tm * 8 + i;
            if (grow < N) {
                float s = dinv[grow];
                ushort4 v;
                v.x = f2bf(acc[i][0] * s);
                v.y = f2bf(acc[i][1] * s);
                v.z = f2bf(acc[i][2] * s);
                v.w = f2bf(acc[i][3] * s);
                *(ushort4*)(outb + (size_t)grow * 64 + tn * 4) = v;
            }
        }
        __syncthreads();
    }
}

// ---------------- phase: gather (4 lanes/node x 2 uint4) ----------------
__device__ void ph_gather(int gtid, int gsz,
                          const uint4* __restrict__ srcq, const int* __restrict__ eros,
                          const int* __restrict__ start, const int* __restrict__ cntarr,
                          const float* __restrict__ dinv, const float* __restrict__ bias,
                          float* __restrict__ dstf, uint4* __restrict__ dstq,
                          int N, int mode) {
    int total = N * 4;
    for (int idx = gtid; idx < total; idx += gsz) {
        int node = idx >> 2;
        int l = idx & 3;

        float a[16];
        {
            uint4 s0 = srcq[(size_t)node * 8 + l * 2];
            uint4 s1 = srcq[(size_t)node * 8 + l * 2 + 1];
            a[0] = bflo(s0.x); a[1] = bfhi(s0.x);
            a[2] = bflo(s0.y); a[3] = bfhi(s0.y);
            a[4] = bflo(s0.z); a[5] = bfhi(s0.z);
            a[6] = bflo(s0.w); a[7] = bfhi(s0.w);
            a[8] = bflo(s1.x); a[9] = bfhi(s1.x);
            a[10] = bflo(s1.y); a[11] = bfhi(s1.y);
            a[12] = bflo(s1.z); a[13] = bfhi(s1.z);
            a[14] = bflo(s1.w); a[15] = bfhi(s1.w);
        }

        int e = start[node];
        int eend = e + cntarr[node];
        for (; e + 8 <= eend; e += 8) {
            uint4 v0[8], v1[8];
#pragma unroll
            for (int j = 0; j < 8; ++j) {
                int r = eros[e + j];
                const uint4* p = srcq + (size_t)r * 8 + l * 2;
                v0[j] = p[0];
                v1[j] = p[1];
            }
#pragma unroll
            for (int j = 0; j < 8; ++j) {
                a[0] += bflo(v0[j].x); a[1] += bfhi(v0[j].x);
                a[2] += bflo(v0[j].y); a[3] += bfhi(v0[j].y);
                a[4] += bflo(v0[j].z); a[5] += bfhi(v0[j].z);
                a[6] += bflo(v0[j].w); a[7] += bfhi(v0[j].w);
                a[8] += bflo(v1[j].x); a[9] += bfhi(v1[j].x);
                a[10] += bflo(v1[j].y); a[11] += bfhi(v1[j].y);
                a[12] += bflo(v1[j].z); a[13] += bfhi(v1[j].z);
                a[14] += bflo(v1[j].w); a[15] += bfhi(v1[j].w);
            }
        }
        for (; e + 4 <= eend; e += 4) {
            uint4 v0[4], v1[4];
#pragma unroll
            for (int j = 0; j < 4; ++j) {
                int r = eros[e + j];
                const uint4* p = srcq + (size_t)r * 8 + l * 2;
                v0[j] = p[0];
                v1[j] = p[1];
            }
#pragma unroll
            for (int j = 0; j < 4; ++j) {
                a[0] += bflo(v0[j].x); a[1] += bfhi(v0[j].x);
                a[2] += bflo(v0[j].y); a[3] += bfhi(v0[j].y);
                a[4] += bflo(v0[j].z); a[5] += bfhi(v0[j].z);
                a[6] += bflo(v0[j].w); a[7] += bfhi(v0[j].w);
                a[8] += bflo(v1[j].x); a[9] += bfhi(v1[j].x);
                a[10] += bflo(v1[j].y); a[11] += bfhi(v1[j].y);
                a[12] += bflo(v1[j].z); a[13] += bfhi(v1[j].z);
                a[14] += bflo(v1[j].w); a[15] += bfhi(v1[j].w);
            }
        }
        for (; e < eend; ++e) {
            int r = eros[e];
            const uint4* p = srcq + (size_t)r * 8 + l * 2;
            uint4 v0 = p[0], v1 = p[1];
            a[0] += bflo(v0.x); a[1] += bfhi(v0.x);
            a[2] += bflo(v0.y); a[3] += bfhi(v0.y);
            a[4] += bflo(v0.z); a[5] += bfhi(v0.z);
            a[6] += bflo(v0.w); a[7] += bfhi(v0.w);
            a[8] += bflo(v1.x); a[9] += bfhi(v1.x);
            a[10] += bflo(v1.y); a[11] += bfhi(v1.y);
            a[12] += bflo(v1.z); a[13] += bfhi(v1.z);
            a[14] += bflo(v1.w); a[15] += bfhi(v1.w);
        }
        float sc = dinv[node];
        const float4* bp = (const float4*)bias;
#pragma unroll
        for (int q = 0; q < 4; ++q) {
            float4 bq = bp[l * 4 + q];
            a[q * 4 + 0] = a[q * 4 + 0] * sc + bq.x;
            a[q * 4 + 1] = a[q * 4 + 1] * sc + bq.y;
            a[q * 4 + 2] = a[q * 4 + 2] * sc + bq.z;
            a[q * 4 + 3] = a[q * 4 + 3] * sc + bq.w;
        }
        if (mode) {  // relu + bf16 pack
#pragma unroll
            for (int i = 0; i < 16; ++i) a[i] = fmaxf(a[i], 0.f);
            uint4 o0, o1;
            o0.x = (unsigned)f2bf(a[0]) | ((unsigned)f2bf(a[1]) << 16);
            o0.y = (unsigned)f2bf(a[2]) | ((unsigned)f2bf(a[3]) << 16);
            o0.z = (unsigned)f2bf(a[4]) | ((unsigned)f2bf(a[5]) << 16);
            o0.w = (unsigned)f2bf(a[6]) | ((unsigned)f2bf(a[7]) << 16);
            o1.x = (unsigned)f2bf(a[8]) | ((unsigned)f2bf(a[9]) << 16);
            o1.y = (unsigned)f2bf(a[10]) | ((unsigned)f2bf(a[11]) << 16);
            o1.z = (unsigned)f2bf(a[12]) | ((unsigned)f2bf(a[13]) << 16);
            o1.w = (unsigned)f2bf(a[14]) | ((unsigned)f2bf(a[15]) << 16);
            dstq[(size_t)node * 8 + l * 2] = o0;
            dstq[(size_t)node * 8 + l * 2 + 1] = o1;
        } else {
            float4* d = (float4*)(dstf + (size_t)node * 64 + l * 16);
            d[0] = make_float4(a[0], a[1], a[2], a[3]);
            d[1] = make_float4(a[4], a[5], a[6], a[7]);
            d[2] = make_float4(a[8], a[9], a[10], a[11]);
            d[3] = make_float4(a[12], a[13], a[14], a[15]);
        }
    }
}

// ---------------- cooperative mega-kernel ----------------
__global__ __launch_bounds__(NTH, 2) void k_mega(GcnParams p) {
    cg::grid_group grid = cg::this_grid();
    __shared__ __align__(16) char smem[SMEM_BYTES];
    int bId = blockIdx.x, nB = gridDim.x;
    int gtid = bId * NTH + threadIdx.x, gsz = nB * NTH;

    ph_zero(p.cursor, p.nb, gtid, gsz);
    grid.sync();
    ph_bin(smem, bId, nB, p.row, p.col, p.cursor, p.bentries, p.E, p.nchunks);
    grid.sync();
    ph_bsort(smem, bId, nB, p.bentries, p.cursor, p.start, p.cntarr, p.dinv, p.N, p.nb);
    grid.sync();
    ph_gemm_f32(smem, bId, nB, p.x, p.W1, p.dinv, p.Ab, p.N, 128, p.gemmblk);
    grid.sync();
    ph_gather(gtid, gsz, (const uint4*)p.Ab, (const int*)p.bentries,
              p.start, p.cntarr, p.dinv, p.b1, nullptr, (uint4*)p.Hb, p.N, 1);
    grid.sync();
    ph_gemm_bf16(smem, bId, nB, p.Hb, p.W2, p.dinv, p.Ab, p.N, 64, p.gemmblk);
    grid.sync();
    ph_gather(gtid, gsz, (const uint4*)p.Ab, (const int*)p.bentries,
              p.start, p.cntarr, p.dinv, p.b2, p.outf, nullptr, p.N, 0);
}

// ---------------- non-cooperative fallback wrappers ----------------
__global__ __launch_bounds__(NTH) void k_zero_w(GcnParams p) {
    ph_zero(p.cursor, p.nb, blockIdx.x * NTH + threadIdx.x, gridDim.x * NTH);
}
__global__ __launch_bounds__(NTH) void k_bin_w(GcnParams p) {
    __shared__ __align__(16) char smem[SMEM_BYTES];
    ph_bin(smem, blockIdx.x, gridDim.x, p.row, p.col, p.cursor, p.bentries, p.E, p.nchunks);
}
__global__ __launch_bounds__(NTH) void k_bsort_w(GcnParams p) {
    __shared__ __align__(16) char smem[17920];
    ph_bsort(smem, blockIdx.x, gridDim.x, p.bentries, p.cursor, p.start, p.cntarr,
             p.dinv, p.N, p.nb);
}
__global__ __launch_bounds__(NTH) void k_gemm1_w(GcnParams p) {
    __shared__ __align__(16) char smem[25088];
    ph_gemm_f32(smem, blockIdx.x, gridDim.x, p.x, p.W1, p.dinv, p.Ab, p.N, 128, p.gemmblk);
}
__global__ __launch_bounds__(NTH) void k_gemm2_w(GcnParams p) {
    __shared__ __align__(16) char smem[25088];
    ph_gemm_bf16(smem, blockIdx.x, gridDim.x, p.Hb, p.W2, p.dinv, p.Ab, p.N, 64, p.gemmblk);
}
__global__ __launch_bounds__(NTH) void k_gather1_w(GcnParams p) {
    ph_gather(blockIdx.x * NTH + threadIdx.x, gridDim.x * NTH, (const uint4*)p.Ab,
              (const int*)p.bentries, p.start, p.cntarr, p.dinv, p.b1,
              nullptr, (uint4*)p.Hb, p.N, 1);
}
__global__ __launch_bounds__(NTH) void k_gather2_w(GcnParams p) {
    ph_gather(blockIdx.x * NTH + threadIdx.x, gridDim.x * NTH, (const uint4*)p.Ab,
              (const int*)p.bentries, p.start, p.cntarr, p.dinv, p.b2,
              p.outf, nullptr, p.N, 0);
}

extern "C" void kernel_launch(void* const* d_in, const int* in_sizes, int n_in,
                              void* d_out, int out_size, void* d_ws, size_t ws_size,
                              hipStream_t stream) {
    GcnParams p;
    p.x = (const float*)d_in[0];
    const int* ei = (const int*)d_in[1];  // int32 per harness contract, [2, E]
    p.W1 = (const float*)d_in[2];
    p.b1 = (const float*)d_in[3];
    p.W2 = (const float*)d_in[4];
    p.b2 = (const float*)d_in[5];

    p.N = in_sizes[0] / 128;  // 100000
    p.E = in_sizes[1] / 2;    // 1600000
    p.row = ei;
    p.col = ei + p.E;
    p.nb = (p.N + (1 << BKT_SH) - 1) >> BKT_SH;  // 782 buckets
    p.nchunks = (p.E + CHUNK - 1) / CHUNK;       // 521 chunks
    p.gemmblk = (p.N + BM - 1) / BM;             // 782 tiles

    char* ws = (char*)d_ws;
    p.cursor = (int*)ws;                              // nb ints @ 0
    p.start = (int*)(ws + (1 << 16));                 // N ints @ 64 KB
    p.cntarr = (int*)(ws + (1 << 19));                // N ints @ 512 KB
    p.dinv = (float*)(ws + 960 * 1024);               // N floats @ 960 KB
    p.bentries = (unsigned*)(ws + (2 << 20));         // nb*CAP u32 @ 2 MB (12.8 MB)
    p.Ab = (unsigned short*)(ws + (15 << 20));        // N*64 bf16 @ 15 MB
    p.Hb = (unsigned short*)d_out;                    // bf16 h2 scratch in d_out
    p.outf = (float*)d_out;                           // final fp32 output

    // Decide launch mode once (host-side queries; no allocation, capture-safe).
    static int s_mode = -1;   // 1 = cooperative mega-kernel, 0 = 7-launch fallback
    static int s_grid = 256;
    if (s_mode < 0) {
        int dev = 0;
        hipGetDevice(&dev);
        int coop = 0;
        hipDeviceGetAttribute(&coop, hipDeviceAttributeCooperativeLaunch, dev);
        int ncu = 0;
        hipDeviceGetAttribute(&ncu, hipDeviceAttributeMultiprocessorCount, dev);
        int maxb = 0;
        hipError_t e = hipOccupancyMaxActiveBlocksPerMultiprocessor(
            &maxb, reinterpret_cast<const void*>(&k_mega), NTH, 0);
        if (e == hipSuccess && coop && maxb >= 1 && ncu > 0) {
            s_mode = 1;
            s_grid = ncu * (maxb > 2 ? 2 : maxb);
        } else {
            s_mode = 0;
        }
    }

    if (s_mode == 1) {
        void* kargs[] = {&p};
        hipLaunchCooperativeKernel(reinterpret_cast<const void*>(&k_mega),
                                   dim3(s_grid), dim3(NTH), kargs, 0, stream);
    } else {
        int gblk = (p.N * 4 + NTH - 1) / NTH;
        k_zero_w<<<(p.nb + NTH - 1) / NTH, NTH, 0, stream>>>(p);
        k_bin_w<<<p.nchunks, NTH, 0, stream>>>(p);
        k_bsort_w<<<p.nb, NTH, 0, stream>>>(p);
        k_gemm1_w<<<p.gemmblk, NTH, 0, stream>>>(p);
        k_gather1_w<<<gblk, NTH, 0, stream>>>(p);
        k_gemm2_w<<<p.gemmblk, NTH, 0, stream>>>(p);
        k_gather2_w<<<gblk, NTH, 0, stream>>>(p);
    }
}

// Round 7
// 359.811 us; speedup vs baseline: 4.4267x; 1.0307x over previous
//
#include <hip/hip_runtime.h>
#include <hip/hip_cooperative_groups.h>

namespace cg = cooperative_groups;

// GCN 2-layer, single cooperative mega-kernel, occupancy-tuned.
//   out[c] = dinv[c] * ( h_s[c] + sum_{e: col=c} h_s[row_e] ) + b,  h_s=(X@W)*dinv
// R16: R15's mega-kernel failed on OCCUPANCY, not the fusion idea (VGPR 148 +
// 2 blocks/CU clamp -> 8 waves/CU during the latency-bound gather; phases ran
// 2-3x slower; Occupancy 11.9%). Fix: __launch_bounds__(256,5) caps VGPR at
// 102 (gemm ~85 max, no spill), CHUNK 6144->2048 cuts bin LDS to 29.7KB ->
// 5 blocks/CU co-resident, grid = ncu*5 = 1280, 20 waves/CU in every phase.
// Gather = R10-verified 8-lane x uint4 (lowest VGPR, best measured). bin gets
// 3 blocks/CU (was 1). Launch-overhead theory (7 launches x ~12us) unchanged.
// R14 lesson: no LDS-atomic scatter. R11 lesson: no 4B global scatter.
// Messages bf16, accum fp32. Requires N < 2^17. Int inputs arrive as int32.

#define BKT_SH 7            // 128 nodes per bucket
#define BKT_CAP 4096        // region per bucket (counts ~2046 +- 45; huge margin)
#define CHUNK 2048          // edges per bin chunk (782 chunks, 29.7KB LDS)
#define BM 128
#define BK 32
#define NTH 256
#define SMEM_BYTES 29696
#define MAXBLK 5

__device__ __forceinline__ unsigned short f2bf(float f) {
    unsigned u = __builtin_bit_cast(unsigned, f);
    u = (u + 0x7FFF + ((u >> 16) & 1)) >> 16;  // RNE
    return (unsigned short)u;
}
__device__ __forceinline__ float bflo(unsigned u) {  // low bf16 of packed pair
    return __builtin_bit_cast(float, u << 16);
}
__device__ __forceinline__ float bfhi(unsigned u) {  // high bf16 of packed pair
    return __builtin_bit_cast(float, u & 0xFFFF0000u);
}

struct GcnParams {
    const float* x;
    const int* row;
    const int* col;
    const float* W1;
    const float* b1;
    const float* W2;
    const float* b2;
    int* cursor;
    int* start;
    int* cntarr;
    float* dinv;
    unsigned* bentries;
    unsigned short* Ab;
    unsigned short* Hb;   // bf16 h2 scratch (in d_out)
    float* outf;          // final fp32 out (d_out)
    int N, E, nb, nchunks, gemmblk;
};

// ---------------- phase: zero cursor ----------------
__device__ void ph_zero(int* p, int n, int gtid, int gsz) {
    for (int i = gtid; i < n; i += gsz) p[i] = 0;
}

// ---------------- phase: block-chunked binning ----------------
// LDS hist -> scan -> one reservation atomic per (chunk,bucket) -> LDS sort by
// bucket -> run-coalesced writes into fixed region [bkt*CAP, (bkt+1)*CAP).
__device__ void ph_bin(char* smem, int bId, int nB,
                       const int* __restrict__ row, const int* __restrict__ col,
                       int* __restrict__ cursor, unsigned* __restrict__ bentries,
                       int E, int nchunks) {
    unsigned* sorted = (unsigned*)(smem);                  // 8192
    unsigned short* bof = (unsigned short*)(smem + 8192);  // 4096
    int* hist = (int*)(smem + 12288);                      // 4096
    int* ex0 = (int*)(smem + 16384);
    int* cur = (int*)(smem + 20480);
    int* gbase = (int*)(smem + 24576);
    int* tsum = (int*)(smem + 28672);                      // 1024
    int t = threadIdx.x;

    for (int chn = bId; chn < nchunks; chn += nB) {
        int s0 = chn * CHUNK;
        int cnt = E - s0; if (cnt > CHUNK) cnt = CHUNK;

        for (int i = t; i < 1024; i += NTH) hist[i] = 0;
        __syncthreads();
        // pass 1: histogram
        for (int i = t; i < cnt; i += NTH)
            atomicAdd(&hist[col[s0 + i] >> BKT_SH], 1);
        __syncthreads();
        // scan 1024 bins: thread t owns bins [4t, 4t+4)
        {
            int b0 = hist[4 * t], b1 = hist[4 * t + 1];
            int b2 = hist[4 * t + 2], b3 = hist[4 * t + 3];
            int tot = b0 + b1 + b2 + b3;
            tsum[t] = tot;
            __syncthreads();
#pragma unroll
            for (int d = 1; d < 256; d <<= 1) {
                int x = (t >= d) ? tsum[t - d] : 0;
                __syncthreads();
                tsum[t] += (t >= d) ? x : 0;
                __syncthreads();
            }
            int ex = tsum[t] - tot;
            ex0[4 * t] = ex;
            ex0[4 * t + 1] = ex + b0;
            ex0[4 * t + 2] = ex + b0 + b1;
            ex0[4 * t + 3] = ex + b0 + b1 + b2;
            cur[4 * t] = ex0[4 * t];
            cur[4 * t + 1] = ex0[4 * t + 1];
            cur[4 * t + 2] = ex0[4 * t + 2];
            cur[4 * t + 3] = ex0[4 * t + 3];
        }
        __syncthreads();
        // reserve region space: one global atomic per non-empty bucket
        for (int i = t; i < 1024; i += NTH)
            if (hist[i] > 0) gbase[i] = i * BKT_CAP + atomicAdd(&cursor[i], hist[i]);
        // pass 2: LDS sort by bucket
        for (int i = t; i < cnt; i += NTH) {
            int c = col[s0 + i], r = row[s0 + i];
            int bkt = c >> BKT_SH;
            int p = atomicAdd(&cur[bkt], 1);
            sorted[p] = ((unsigned)(c & ((1 << BKT_SH) - 1)) << 17) | (unsigned)r;
            bof[p] = (unsigned short)bkt;
        }
        __syncthreads();
        // pass 3: run-coalesced global writes
        for (int i = t; i < cnt; i += NTH) {
            int bkt = bof[i];
            int pos = gbase[bkt] + (i - ex0[bkt]);
            if (pos < (bkt + 1) * BKT_CAP) bentries[pos] = sorted[i];
        }
        __syncthreads();
    }
}

// ---------------- phase: per-bucket counting sort ----------------
__device__ void ph_bsort(char* smem, int bId, int nB,
                         unsigned* __restrict__ bentries, const int* __restrict__ cursor,
                         int* __restrict__ start, int* __restrict__ cntarr,
                         float* __restrict__ dinv, int N, int nb) {
    int* hist = (int*)(smem);            // 512
    int* incl = (int*)(smem + 512);
    int* cur = (int*)(smem + 1024);
    int* rows = (int*)(smem + 1536);     // 16384
    int t = threadIdx.x;

    for (int b = bId; b < nb; b += nB) {
        int base = b * BKT_CAP;
        int cnt = cursor[b];
        if (cnt > BKT_CAP) cnt = BKT_CAP;

        if (t < 128) hist[t] = 0;
        __syncthreads();
        for (int i = t; i < cnt; i += NTH)
            atomicAdd(&hist[bentries[base + i] >> 17], 1);
        __syncthreads();
        if (t < 128) incl[t] = hist[t];
        __syncthreads();
#pragma unroll
        for (int d = 1; d < 128; d <<= 1) {
            int x = (t < 128 && t >= d) ? incl[t - d] : 0;
            __syncthreads();
            if (t < 128 && t >= d) incl[t] += x;
            __syncthreads();
        }
        if (t < 128) {
            int ex = incl[t] - hist[t];
            int node = (b << BKT_SH) + t;
            if (node < N) {
                start[node] = base + ex;
                cntarr[node] = hist[t];
                dinv[node] = rsqrtf((float)hist[t] + 1.0f);  // +1 self loop
            }
            cur[t] = ex;
        }
        __syncthreads();
        for (int i = t; i < cnt; i += NTH) {
            unsigned en = bentries[base + i];
            int p = atomicAdd(&cur[en >> 17], 1);
            rows[p] = (int)(en & 0x1FFFF);
        }
        __syncthreads();
        for (int i = t; i < cnt; i += NTH) bentries[base + i] = (unsigned)rows[i];
        __syncthreads();
    }
}

// ---------------- phase: GEMM (fp32 in), bf16 out, *dinv ----------------
__device__ void ph_gemm_f32(char* smem, int bId, int nB,
                            const float* __restrict__ X, const float* __restrict__ W,
                            const float* __restrict__ dinv,
                            unsigned short* __restrict__ outb,
                            int N, int K, int gemmblk) {
    float (*Xs)[BM + 4] = (float(*)[BM + 4])(smem);       // 16896
    float (*Ws)[64] = (float(*)[64])(smem + 16896);       // 8192
    int t = threadIdx.x;
    int tm = t >> 4, tn = t & 15;

    for (int tile = bId; tile < gemmblk; tile += nB) {
        int bm = tile * BM;
        float acc[8][4];
#pragma unroll
        for (int i = 0; i < 8; ++i)
#pragma unroll
            for (int j = 0; j < 4; ++j) acc[i][j] = 0.f;

        for (int kb = 0; kb < K; kb += BK) {
#pragma unroll
            for (int it = 0; it < 4; ++it) {
                int r = (t >> 3) + 32 * it;
                int grow = bm + r;
                int k4 = t & 7;
                float4 v = make_float4(0.f, 0.f, 0.f, 0.f);
                if (grow < N) v = *(const float4*)(X + (size_t)grow * K + kb + k4 * 4);
                Xs[k4 * 4 + 0][r] = v.x;
                Xs[k4 * 4 + 1][r] = v.y;
                Xs[k4 * 4 + 2][r] = v.z;
                Xs[k4 * 4 + 3][r] = v.w;
            }
#pragma unroll
            for (int it = 0; it < 2; ++it) {
                int idx = t + NTH * it;
                ((float4*)Ws)[idx] = ((const float4*)(W + (size_t)kb * 64))[idx];
            }
            __syncthreads();
#pragma unroll
            for (int k = 0; k < BK; ++k) {
                float4 xa = *(const float4*)&Xs[k][tm * 8];
                float4 xb = *(const float4*)&Xs[k][tm * 8 + 4];
                float4 w = *(const float4*)&Ws[k][tn * 4];
                float xs[8] = {xa.x, xa.y, xa.z, xa.w, xb.x, xb.y, xb.z, xb.w};
#pragma unroll
                for (int i = 0; i < 8; ++i) {
                    acc[i][0] = fmaf(xs[i], w.x, acc[i][0]);
                    acc[i][1] = fmaf(xs[i], w.y, acc[i][1]);
                    acc[i][2] = fmaf(xs[i], w.z, acc[i][2]);
                    acc[i][3] = fmaf(xs[i], w.w, acc[i][3]);
                }
            }
            __syncthreads();
        }
#pragma unroll
        for (int i = 0; i < 8; ++i) {
            int grow = bm + tm * 8 + i;
            if (grow < N) {
                float s = dinv[grow];
                ushort4 v;
                v.x = f2bf(acc[i][0] * s);
                v.y = f2bf(acc[i][1] * s);
                v.z = f2bf(acc[i][2] * s);
                v.w = f2bf(acc[i][3] * s);
                *(ushort4*)(outb + (size_t)grow * 64 + tn * 4) = v;
            }
        }
        __syncthreads();
    }
}

// ---------------- phase: GEMM (bf16 in), bf16 out, *dinv ----------------
__device__ void ph_gemm_bf16(char* smem, int bId, int nB,
                             const unsigned short* __restrict__ Xb,
                             const float* __restrict__ W,
                             const float* __restrict__ dinv,
                             unsigned short* __restrict__ outb,
                             int N, int K, int gemmblk) {
    float (*Xs)[BM + 4] = (float(*)[BM + 4])(smem);
    float (*Ws)[64] = (float(*)[64])(smem + 16896);
    int t = threadIdx.x;
    int tm = t >> 4, tn = t & 15;

    for (int tile = bId; tile < gemmblk; tile += nB) {
        int bm = tile * BM;
        float acc[8][4];
#pragma unroll
        for (int i = 0; i < 8; ++i)
#pragma unroll
            for (int j = 0; j < 4; ++j) acc[i][j] = 0.f;

        for (int kb = 0; kb < K; kb += BK) {
#pragma unroll
            for (int it = 0; it < 2; ++it) {
                int idx = t * 2 + it;
                int r = idx >> 2;
                int q = idx & 3;
                int grow = bm + r;
                uint4 v = make_uint4(0u, 0u, 0u, 0u);
                if (grow < N) v = *(const uint4*)(Xb + (size_t)grow * K + kb + q * 8);
                int k0 = q * 8;
                Xs[k0 + 0][r] = bflo(v.x); Xs[k0 + 1][r] = bfhi(v.x);
                Xs[k0 + 2][r] = bflo(v.y); Xs[k0 + 3][r] = bfhi(v.y);
                Xs[k0 + 4][r] = bflo(v.z); Xs[k0 + 5][r] = bfhi(v.z);
                Xs[k0 + 6][r] = bflo(v.w); Xs[k0 + 7][r] = bfhi(v.w);
            }
#pragma unroll
            for (int it = 0; it < 2; ++it) {
                int idx = t + NTH * it;
                ((float4*)Ws)[idx] = ((const float4*)(W + (size_t)kb * 64))[idx];
            }
            __syncthreads();
#pragma unroll
            for (int k = 0; k < BK; ++k) {
                float4 xa = *(const float4*)&Xs[k][tm * 8];
                float4 xb = *(const float4*)&Xs[k][tm * 8 + 4];
                float4 w = *(const float4*)&Ws[k][tn * 4];
                float xs[8] = {xa.x, xa.y, xa.z, xa.w, xb.x, xb.y, xb.z, xb.w};
#pragma unroll
                for (int i = 0; i < 8; ++i) {
                    acc[i][0] = fmaf(xs[i], w.x, acc[i][0]);
                    acc[i][1] = fmaf(xs[i], w.y, acc[i][1]);
                    acc[i][2] = fmaf(xs[i], w.z, acc[i][2]);
                    acc[i][3] = fmaf(xs[i], w.w, acc[i][3]);
                }
            }
            __syncthreads();
        }
#pragma unroll
        for (int i = 0; i < 8; ++i) {
            int grow = bm + tm * 8 + i;
            if (grow < N) {
                float s = dinv[grow];
                ushort4 v;
                v.x = f2bf(acc[i][0] * s);
                v.y = f2bf(acc[i][1] * s);
                v.z = f2bf(acc[i][2] * s);
                v.w = f2bf(acc[i][3] * s);
                *(ushort4*)(outb + (size_t)grow * 64 + tn * 4) = v;
            }
        }
        __syncthreads();
    }
}

// ---------------- phase: gather (8 lanes/node x 1 uint4, R10-verified) ------
__device__ void ph_gather(int gtid, int gsz,
                          const uint4* __restrict__ srcq, const int* __restrict__ eros,
                          const int* __restrict__ start, const int* __restrict__ cntarr,
                          const float* __restrict__ dinv, const float* __restrict__ bias,
                          float* __restrict__ dstf, uint4* __restrict__ dstq,
                          int N, int mode) {
    int total = N * 8;
    for (int idx = gtid; idx < total; idx += gsz) {
        int node = idx >> 3;
        int l = idx & 7;

        uint4 sv = srcq[(size_t)node * 8 + l];  // self loop
        float a0 = bflo(sv.x), a1 = bfhi(sv.x);
        float a2 = bflo(sv.y), a3 = bfhi(sv.y);
        float a4 = bflo(sv.z), a5 = bfhi(sv.z);
        float a6 = bflo(sv.w), a7 = bfhi(sv.w);

        int e = start[node];
        int eend = e + cntarr[node];
        for (; e + 8 <= eend; e += 8) {
            uint4 v[8];
#pragma unroll
            for (int j = 0; j < 8; ++j) {
                int r = eros[e + j];
                v[j] = srcq[(size_t)r * 8 + l];
            }
#pragma unroll
            for (int j = 0; j < 8; ++j) {
                a0 += bflo(v[j].x); a1 += bfhi(v[j].x);
                a2 += bflo(v[j].y); a3 += bfhi(v[j].y);
                a4 += bflo(v[j].z); a5 += bfhi(v[j].z);
                a6 += bflo(v[j].w); a7 += bfhi(v[j].w);
            }
        }
        for (; e + 4 <= eend; e += 4) {
            uint4 v[4];
#pragma unroll
            for (int j = 0; j < 4; ++j) {
                int r = eros[e + j];
                v[j] = srcq[(size_t)r * 8 + l];
            }
#pragma unroll
            for (int j = 0; j < 4; ++j) {
                a0 += bflo(v[j].x); a1 += bfhi(v[j].x);
                a2 += bflo(v[j].y); a3 += bfhi(v[j].y);
                a4 += bflo(v[j].z); a5 += bfhi(v[j].z);
                a6 += bflo(v[j].w); a7 += bfhi(v[j].w);
            }
        }
        for (; e < eend; ++e) {
            int r = eros[e];
            uint4 v = srcq[(size_t)r * 8 + l];
            a0 += bflo(v.x); a1 += bfhi(v.x);
            a2 += bflo(v.y); a3 += bfhi(v.y);
            a4 += bflo(v.z); a5 += bfhi(v.z);
            a6 += bflo(v.w); a7 += bfhi(v.w);
        }
        float sc = dinv[node];
        const float4* bp = (const float4*)bias;
        float4 b0 = bp[l * 2], b1 = bp[l * 2 + 1];
        a0 = a0 * sc + b0.x; a1 = a1 * sc + b0.y;
        a2 = a2 * sc + b0.z; a3 = a3 * sc + b0.w;
        a4 = a4 * sc + b1.x; a5 = a5 * sc + b1.y;
        a6 = a6 * sc + b1.z; a7 = a7 * sc + b1.w;
        if (mode) {  // relu + bf16 pack
            a0 = fmaxf(a0, 0.f); a1 = fmaxf(a1, 0.f);
            a2 = fmaxf(a2, 0.f); a3 = fmaxf(a3, 0.f);
            a4 = fmaxf(a4, 0.f); a5 = fmaxf(a5, 0.f);
            a6 = fmaxf(a6, 0.f); a7 = fmaxf(a7, 0.f);
            uint4 o;
            o.x = (unsigned)f2bf(a0) | ((unsigned)f2bf(a1) << 16);
            o.y = (unsigned)f2bf(a2) | ((unsigned)f2bf(a3) << 16);
            o.z = (unsigned)f2bf(a4) | ((unsigned)f2bf(a5) << 16);
            o.w = (unsigned)f2bf(a6) | ((unsigned)f2bf(a7) << 16);
            dstq[(size_t)node * 8 + l] = o;
        } else {
            float4 o0 = make_float4(a0, a1, a2, a3);
            float4 o1 = make_float4(a4, a5, a6, a7);
            float4* d = (float4*)(dstf + (size_t)node * 64 + l * 8);
            d[0] = o0;
            d[1] = o1;
        }
    }
}

// ---------------- cooperative mega-kernel ----------------
__global__ __launch_bounds__(NTH, MAXBLK) void k_mega(GcnParams p) {
    cg::grid_group grid = cg::this_grid();
    __shared__ __align__(16) char smem[SMEM_BYTES];
    int bId = blockIdx.x, nB = gridDim.x;
    int gtid = bId * NTH + threadIdx.x, gsz = nB * NTH;

    ph_zero(p.cursor, p.nb, gtid, gsz);
    grid.sync();
    ph_bin(smem, bId, nB, p.row, p.col, p.cursor, p.bentries, p.E, p.nchunks);
    grid.sync();
    ph_bsort(smem, bId, nB, p.bentries, p.cursor, p.start, p.cntarr, p.dinv, p.N, p.nb);
    grid.sync();
    ph_gemm_f32(smem, bId, nB, p.x, p.W1, p.dinv, p.Ab, p.N, 128, p.gemmblk);
    grid.sync();
    ph_gather(gtid, gsz, (const uint4*)p.Ab, (const int*)p.bentries,
              p.start, p.cntarr, p.dinv, p.b1, nullptr, (uint4*)p.Hb, p.N, 1);
    grid.sync();
    ph_gemm_bf16(smem, bId, nB, p.Hb, p.W2, p.dinv, p.Ab, p.N, 64, p.gemmblk);
    grid.sync();
    ph_gather(gtid, gsz, (const uint4*)p.Ab, (const int*)p.bentries,
              p.start, p.cntarr, p.dinv, p.b2, p.outf, nullptr, p.N, 0);
}

// ---------------- non-cooperative fallback wrappers ----------------
__global__ __launch_bounds__(NTH) void k_zero_w(GcnParams p) {
    ph_zero(p.cursor, p.nb, blockIdx.x * NTH + threadIdx.x, gridDim.x * NTH);
}
__global__ __launch_bounds__(NTH) void k_bin_w(GcnParams p) {
    __shared__ __align__(16) char smem[SMEM_BYTES];
    ph_bin(smem, blockIdx.x, gridDim.x, p.row, p.col, p.cursor, p.bentries, p.E, p.nchunks);
}
__global__ __launch_bounds__(NTH) void k_bsort_w(GcnParams p) {
    __shared__ __align__(16) char smem[17920];
    ph_bsort(smem, blockIdx.x, gridDim.x, p.bentries, p.cursor, p.start, p.cntarr,
             p.dinv, p.N, p.nb);
}
__global__ __launch_bounds__(NTH) void k_gemm1_w(GcnParams p) {
    __shared__ __align__(16) char smem[25088];
    ph_gemm_f32(smem, blockIdx.x, gridDim.x, p.x, p.W1, p.dinv, p.Ab, p.N, 128, p.gemmblk);
}
__global__ __launch_bounds__(NTH) void k_gemm2_w(GcnParams p) {
    __shared__ __align__(16) char smem[25088];
    ph_gemm_bf16(smem, blockIdx.x, gridDim.x, p.Hb, p.W2, p.dinv, p.Ab, p.N, 64, p.gemmblk);
}
__global__ __launch_bounds__(NTH) void k_gather1_w(GcnParams p) {
    ph_gather(blockIdx.x * NTH + threadIdx.x, gridDim.x * NTH, (const uint4*)p.Ab,
              (const int*)p.bentries, p.start, p.cntarr, p.dinv, p.b1,
              nullptr, (uint4*)p.Hb, p.N, 1);
}
__global__ __launch_bounds__(NTH) void k_gather2_w(GcnParams p) {
    ph_gather(blockIdx.x * NTH + threadIdx.x, gridDim.x * NTH, (const uint4*)p.Ab,
              (const int*)p.bentries, p.start, p.cntarr, p.dinv, p.b2,
              p.outf, nullptr, p.N, 0);
}

extern "C" void kernel_launch(void* const* d_in, const int* in_sizes, int n_in,
                              void* d_out, int out_size, void* d_ws, size_t ws_size,
                              hipStream_t stream) {
    GcnParams p;
    p.x = (const float*)d_in[0];
    const int* ei = (const int*)d_in[1];  // int32 per harness contract, [2, E]
    p.W1 = (const float*)d_in[2];
    p.b1 = (const float*)d_in[3];
    p.W2 = (const float*)d_in[4];
    p.b2 = (const float*)d_in[5];

    p.N = in_sizes[0] / 128;  // 100000
    p.E = in_sizes[1] / 2;    // 1600000
    p.row = ei;
    p.col = ei + p.E;
    p.nb = (p.N + (1 << BKT_SH) - 1) >> BKT_SH;  // 782 buckets
    p.nchunks = (p.E + CHUNK - 1) / CHUNK;       // 782 chunks
    p.gemmblk = (p.N + BM - 1) / BM;             // 782 tiles

    char* ws = (char*)d_ws;
    p.cursor = (int*)ws;                              // nb ints @ 0
    p.start = (int*)(ws + (1 << 16));                 // N ints @ 64 KB
    p.cntarr = (int*)(ws + (1 << 19));                // N ints @ 512 KB
    p.dinv = (float*)(ws + 960 * 1024);               // N floats @ 960 KB
    p.bentries = (unsigned*)(ws + (2 << 20));         // nb*CAP u32 @ 2 MB (12.8 MB)
    p.Ab = (unsigned short*)(ws + (15 << 20));        // N*64 bf16 @ 15 MB
    p.Hb = (unsigned short*)d_out;                    // bf16 h2 scratch in d_out
    p.outf = (float*)d_out;                           // final fp32 output

    // Decide launch mode once (host-side queries; no allocation, capture-safe).
    static int s_mode = -1;   // 1 = cooperative mega-kernel, 0 = 7-launch fallback
    static int s_grid = 256;
    if (s_mode < 0) {
        int dev = 0;
        hipGetDevice(&dev);
        int coop = 0;
        hipDeviceGetAttribute(&coop, hipDeviceAttributeCooperativeLaunch, dev);
        int ncu = 0;
        hipDeviceGetAttribute(&ncu, hipDeviceAttributeMultiprocessorCount, dev);
        int maxb = 0;
        hipError_t e = hipOccupancyMaxActiveBlocksPerMultiprocessor(
            &maxb, reinterpret_cast<const void*>(&k_mega), NTH, 0);
        if (e == hipSuccess && coop && maxb >= 1 && ncu > 0) {
            s_mode = 1;
            s_grid = ncu * (maxb > MAXBLK ? MAXBLK : maxb);
        } else {
            s_mode = 0;
        }
    }

    if (s_mode == 1) {
        void* kargs[] = {&p};
        hipLaunchCooperativeKernel(reinterpret_cast<const void*>(&k_mega),
                                   dim3(s_grid), dim3(NTH), kargs, 0, stream);
    } else {
        int gblk = (p.N * 8 + NTH - 1) / NTH;
        k_zero_w<<<(p.nb + NTH - 1) / NTH, NTH, 0, stream>>>(p);
        k_bin_w<<<p.nchunks, NTH, 0, stream>>>(p);
        k_bsort_w<<<p.nb, NTH, 0, stream>>>(p);
        k_gemm1_w<<<p.gemmblk, NTH, 0, stream>>>(p);
        k_gather1_w<<<gblk, NTH, 0, stream>>>(p);
        k_gemm2_w<<<p.gemmblk, NTH, 0, stream>>>(p);
        k_gather2_w<<<gblk, NTH, 0, stream>>>(p);
    }
}

// Round 8
// 234.706 us; speedup vs baseline: 6.7863x; 1.5330x over previous
//
#include <hip/hip_runtime.h>

// GCN 2-layer, CSR-gather formulation, padded-bucket CSR build.
//   out[c] = dinv[c] * ( h_s[c] + sum_{e: col=c} h_s[row_e] ) + b,  h_s=(X@W)*dinv
// R17: R10/R12 verified 7-kernel structure; build-chain occupancy fix only.
// Attribution: gathers 2x41us, gemms ~20, zero ~2 -> bin+bsort ~80 (each ~40,
// hiding under the 42us fillBuffer top-5 cutoff). Cause: k_bin 53KB LDS +
// grid 261 -> 1 block/CU (4 waves) on a latency-bound stream; k_bsort 12
// waves/CU atomic-bound. Fix: k_bin block 256->1024 (16 waves/CU, scan kept
// on t<256 with sync-safe guards; CHUNK stays 6144 to preserve 24B-run write
// coalescing), k_bsort block 256->512 (24 waves/CU, scan on t<128).
// Lessons: R11 no 4B global scatter (97MB write amp); R14 no LDS-atomic
// scatter (1.6M conflicts); R15/R16 no mega-fusion (one VGPR/LDS envelope
// cannot serve gather@32waves and gemm@148VGPR simultaneously).
// Messages bf16, accum fp32. Requires N < 2^17. Int inputs arrive as int32.

#define BKT_SH 7            // 128 nodes per bucket
#define BKT_CAP 4096        // region per bucket (counts ~2046 +- 45; huge margin)
#define CHUNK 6144          // edges per k_bin block
#define NTB 1024            // k_bin threads
#define NTS 512             // k_bucket_sort threads
#define BM 128
#define BK 32

__device__ __forceinline__ unsigned short f2bf(float f) {
    unsigned u = __builtin_bit_cast(unsigned, f);
    u = (u + 0x7FFF + ((u >> 16) & 1)) >> 16;  // RNE
    return (unsigned short)u;
}
__device__ __forceinline__ float bflo(unsigned u) {  // low bf16 of packed pair
    return __builtin_bit_cast(float, u << 16);
}
__device__ __forceinline__ float bfhi(unsigned u) {  // high bf16 of packed pair
    return __builtin_bit_cast(float, u & 0xFFFF0000u);
}

__global__ __launch_bounds__(256) void k_zero_i(int* __restrict__ p, int n) {
    int i = blockIdx.x * 256 + threadIdx.x;
    if (i < n) p[i] = 0;
}

// (A) block-chunked binning, 1024 threads: LDS hist -> LDS scan (t<256) ->
// one count-reservation atomic per (block,bucket) -> LDS sort by bucket ->
// run-coalesced writes into fixed bucket region [bkt*CAP, (bkt+1)*CAP).
__global__ __launch_bounds__(NTB) void k_bin(const int* __restrict__ row,
                                             const int* __restrict__ col,
                                             int* __restrict__ cursor,
                                             unsigned* __restrict__ bentries,
                                             int E) {
    __shared__ unsigned sorted[CHUNK];        // 24 KB packed entries, bucket order
    __shared__ unsigned short bof[CHUNK];     // 12 KB bucket of sorted[i]
    __shared__ int hist[1024];
    __shared__ int ex0[1024];
    __shared__ int cur[1024];
    __shared__ int gbase[1024];
    __shared__ int tsum[256];
    int b = blockIdx.x, t = threadIdx.x;
    int s0 = b * CHUNK;
    int cnt = E - s0; if (cnt > CHUNK) cnt = CHUNK;

    if (t < 1024) hist[t] = 0;
    __syncthreads();
    // pass 1: histogram
    for (int i = t; i < cnt; i += NTB)
        atomicAdd(&hist[col[s0 + i] >> BKT_SH], 1);
    __syncthreads();
    // scan 1024 bins on threads t<256 (each owns bins [4t, 4t+4));
    // all threads execute the __syncthreads.
    {
        int b0 = 0, b1 = 0, b2 = 0, b3 = 0, tot = 0;
        if (t < 256) {
            b0 = hist[4 * t]; b1 = hist[4 * t + 1];
            b2 = hist[4 * t + 2]; b3 = hist[4 * t + 3];
            tot = b0 + b1 + b2 + b3;
            tsum[t] = tot;
        }
        __syncthreads();
#pragma unroll
        for (int d = 1; d < 256; d <<= 1) {
            int x = 0;
            if (t < 256 && t >= d) x = tsum[t - d];
            __syncthreads();
            if (t < 256 && t >= d) tsum[t] += x;
            __syncthreads();
        }
        if (t < 256) {
            int ex = tsum[t] - tot;  // exclusive across thread groups
            ex0[4 * t] = ex;
            ex0[4 * t + 1] = ex + b0;
            ex0[4 * t + 2] = ex + b0 + b1;
            ex0[4 * t + 3] = ex + b0 + b1 + b2;
            cur[4 * t] = ex;
            cur[4 * t + 1] = ex + b0;
            cur[4 * t + 2] = ex + b0 + b1;
            cur[4 * t + 3] = ex + b0 + b1 + b2;
        }
    }
    __syncthreads();
    // reserve: one atomic per non-empty (block,bucket); region base is fixed
    if (t < 1024)
        if (hist[t] > 0) gbase[t] = t * BKT_CAP + atomicAdd(&cursor[t], hist[t]);
    // pass 2: LDS sort by bucket (order within bucket irrelevant)
    for (int i = t; i < cnt; i += NTB) {
        int c = col[s0 + i], r = row[s0 + i];
        int bkt = c >> BKT_SH;
        int p = atomicAdd(&cur[bkt], 1);
        sorted[p] = ((unsigned)(c & ((1 << BKT_SH) - 1)) << 17) | (unsigned)r;
        bof[p] = (unsigned short)bkt;
    }
    __syncthreads();
    // pass 3: run-coalesced global writes (guard against region overflow)
    for (int i = t; i < cnt; i += NTB) {
        int bkt = bof[i];
        int pos = gbase[bkt] + (i - ex0[bkt]);
        if (pos < (bkt + 1) * BKT_CAP) bentries[pos] = sorted[i];
    }
}

// (B) per-bucket counting sort IN PLACE, 512 threads: bentries[b*CAP..] ->
// row indices sorted by destination node; emits start/cnt/dinv per node.
__global__ __launch_bounds__(NTS) void k_bucket_sort(
    unsigned* __restrict__ bentries, const int* __restrict__ cursor,
    int* __restrict__ start, int* __restrict__ cntarr,
    float* __restrict__ dinv, int N) {
    __shared__ int hist[128];
    __shared__ int incl[128];
    __shared__ int cur[128];
    __shared__ int rows[BKT_CAP];  // 16 KB
    int b = blockIdx.x, t = threadIdx.x;
    int base = b * BKT_CAP;
    int cnt = cursor[b];
    if (cnt > BKT_CAP) cnt = BKT_CAP;  // safety clamp (never expected)

    if (t < 128) hist[t] = 0;
    __syncthreads();
    for (int i = t; i < cnt; i += NTS)
        atomicAdd(&hist[bentries[base + i] >> 17], 1);
    __syncthreads();
    if (t < 128) incl[t] = hist[t];
    __syncthreads();
#pragma unroll
    for (int d = 1; d < 128; d <<= 1) {
        int x = (t < 128 && t >= d) ? incl[t - d] : 0;
        __syncthreads();
        if (t < 128 && t >= d) incl[t] += x;
        __syncthreads();
    }
    if (t < 128) {
        int ex = incl[t] - hist[t];  // exclusive within bucket
        int node = (b << BKT_SH) + t;
        if (node < N) {
            start[node] = base + ex;
            cntarr[node] = hist[t];
            dinv[node] = rsqrtf((float)hist[t] + 1.0f);  // +1 self loop
        }
        cur[t] = ex;
    }
    __syncthreads();
    for (int i = t; i < cnt; i += NTS) {
        unsigned en = bentries[base + i];
        int p = atomicAdd(&cur[en >> 17], 1);
        rows[p] = (int)(en & 0x1FFFF);
    }
    __syncthreads();
    for (int i = t; i < cnt; i += NTS) bentries[base + i] = (unsigned)rows[i];
}

// Tiled GEMM + row scale, fp32 input, bf16 output.
// Block = 256 threads -> BM=128 rows x 64 cols. K chunked by BK=32.
__global__ __launch_bounds__(256) void k_gemm_f32in(
    const float* __restrict__ X, const float* __restrict__ W,
    const float* __restrict__ dinv, unsigned short* __restrict__ outb,
    int N, int K) {
    __shared__ float Xs[BK][BM + 4];
    __shared__ float Ws[BK][64];
    int t = threadIdx.x;
    int bm = blockIdx.x * BM;
    int tm = t >> 4, tn = t & 15;

    float acc[8][4];
#pragma unroll
    for (int i = 0; i < 8; ++i)
#pragma unroll
        for (int j = 0; j < 4; ++j) acc[i][j] = 0.f;

    for (int kb = 0; kb < K; kb += BK) {
#pragma unroll
        for (int it = 0; it < 4; ++it) {
            int r = (t >> 3) + 32 * it;       // 0..127
            int grow = bm + r;
            int k4 = t & 7;                   // float4 index within BK
            float4 v = make_float4(0.f, 0.f, 0.f, 0.f);
            if (grow < N) v = *(const float4*)(X + (size_t)grow * K + kb + k4 * 4);
            Xs[k4 * 4 + 0][r] = v.x;
            Xs[k4 * 4 + 1][r] = v.y;
            Xs[k4 * 4 + 2][r] = v.z;
            Xs[k4 * 4 + 3][r] = v.w;
        }
#pragma unroll
        for (int it = 0; it < 2; ++it) {
            int idx = t + 256 * it;           // 0..511 float4s
            ((float4*)Ws)[idx] = ((const float4*)(W + (size_t)kb * 64))[idx];
        }
        __syncthreads();
#pragma unroll
        for (int k = 0; k < BK; ++k) {
            float4 xa = *(const float4*)&Xs[k][tm * 8];
            float4 xb = *(const float4*)&Xs[k][tm * 8 + 4];
            float4 w = *(const float4*)&Ws[k][tn * 4];
            float xs[8] = {xa.x, xa.y, xa.z, xa.w, xb.x, xb.y, xb.z, xb.w};
#pragma unroll
            for (int i = 0; i < 8; ++i) {
                acc[i][0] = fmaf(xs[i], w.x, acc[i][0]);
                acc[i][1] = fmaf(xs[i], w.y, acc[i][1]);
                acc[i][2] = fmaf(xs[i], w.z, acc[i][2]);
                acc[i][3] = fmaf(xs[i], w.w, acc[i][3]);
            }
        }
        __syncthreads();
    }
#pragma unroll
    for (int i = 0; i < 8; ++i) {
        int grow = bm + tm * 8 + i;
        if (grow < N) {
            float s = dinv[grow];
            ushort4 v;
            v.x = f2bf(acc[i][0] * s);
            v.y = f2bf(acc[i][1] * s);
            v.z = f2bf(acc[i][2] * s);
            v.w = f2bf(acc[i][3] * s);
            *(ushort4*)(outb + (size_t)grow * 64 + tn * 4) = v;
        }
    }
}

// Tiled GEMM + row scale, bf16 input, bf16 output. Same tile shape.
__global__ __launch_bounds__(256) void k_gemm_bf16in(
    const unsigned short* __restrict__ Xb, const float* __restrict__ W,
    const float* __restrict__ dinv, unsigned short* __restrict__ outb,
    int N, int K) {
    __shared__ float Xs[BK][BM + 4];
    __shared__ float Ws[BK][64];
    int t = threadIdx.x;
    int bm = blockIdx.x * BM;
    int tm = t >> 4, tn = t & 15;

    float acc[8][4];
#pragma unroll
    for (int i = 0; i < 8; ++i)
#pragma unroll
        for (int j = 0; j < 4; ++j) acc[i][j] = 0.f;

    for (int kb = 0; kb < K; kb += BK) {
        // 128 rows x 32 k bf16 = 512 uint4 (8 bf16 each); 2 per thread
#pragma unroll
        for (int it = 0; it < 2; ++it) {
            int idx = t * 2 + it;             // 0..511
            int r = idx >> 2;                 // 0..127
            int q = idx & 3;                  // 16B chunk: k = q*8..q*8+8
            int grow = bm + r;
            uint4 v = make_uint4(0u, 0u, 0u, 0u);
            if (grow < N) v = *(const uint4*)(Xb + (size_t)grow * K + kb + q * 8);
            int k0 = q * 8;
            Xs[k0 + 0][r] = bflo(v.x); Xs[k0 + 1][r] = bfhi(v.x);
            Xs[k0 + 2][r] = bflo(v.y); Xs[k0 + 3][r] = bfhi(v.y);
            Xs[k0 + 4][r] = bflo(v.z); Xs[k0 + 5][r] = bfhi(v.z);
            Xs[k0 + 6][r] = bflo(v.w); Xs[k0 + 7][r] = bfhi(v.w);
        }
#pragma unroll
        for (int it = 0; it < 2; ++it) {
            int idx = t + 256 * it;           // 0..511 float4s
            ((float4*)Ws)[idx] = ((const float4*)(W + (size_t)kb * 64))[idx];
        }
        __syncthreads();
#pragma unroll
        for (int k = 0; k < BK; ++k) {
            float4 xa = *(const float4*)&Xs[k][tm * 8];
            float4 xb = *(const float4*)&Xs[k][tm * 8 + 4];
            float4 w = *(const float4*)&Ws[k][tn * 4];
            float xs[8] = {xa.x, xa.y, xa.z, xa.w, xb.x, xb.y, xb.z, xb.w};
#pragma unroll
            for (int i = 0; i < 8; ++i) {
                acc[i][0] = fmaf(xs[i], w.x, acc[i][0]);
                acc[i][1] = fmaf(xs[i], w.y, acc[i][1]);
                acc[i][2] = fmaf(xs[i], w.z, acc[i][2]);
                acc[i][3] = fmaf(xs[i], w.w, acc[i][3]);
            }
        }
        __syncthreads();
    }
#pragma unroll
    for (int i = 0; i < 8; ++i) {
        int grow = bm + tm * 8 + i;
        if (grow < N) {
            float s = dinv[grow];
            ushort4 v;
            v.x = f2bf(acc[i][0] * s);
            v.y = f2bf(acc[i][1] * s);
            v.z = f2bf(acc[i][2] * s);
            v.w = f2bf(acc[i][3] * s);
            *(ushort4*)(outb + (size_t)grow * 64 + tn * 4) = v;
        }
    }
}

// Gather-aggregate + fused postproc. 8 lanes/node; lane l owns channels
// [8l, 8l+8) as one uint4 (4 packed bf16 pairs). fp32 accumulate.
// acc init = src[node] (self loop). MLP-unrolled x8 (+x4 tail).
// mode 1: relu + bf16 out (dstq). mode 0: fp32 out (dstf).
__global__ __launch_bounds__(256) void k_gather(
    const uint4* __restrict__ srcq, const int* __restrict__ eros,
    const int* __restrict__ start, const int* __restrict__ cntarr,
    const float* __restrict__ dinv, const float* __restrict__ bias,
    float* __restrict__ dstf, uint4* __restrict__ dstq, int N, int mode) {
    int idx = blockIdx.x * 256 + threadIdx.x;
    int node = idx >> 3;
    if (node >= N) return;
    int l = idx & 7;

    uint4 sv = srcq[(size_t)node * 8 + l];  // self loop
    float a0 = bflo(sv.x), a1 = bfhi(sv.x);
    float a2 = bflo(sv.y), a3 = bfhi(sv.y);
    float a4 = bflo(sv.z), a5 = bfhi(sv.z);
    float a6 = bflo(sv.w), a7 = bfhi(sv.w);

    int e = start[node];
    int eend = e + cntarr[node];
    for (; e + 8 <= eend; e += 8) {
        uint4 v[8];
#pragma unroll
        for (int j = 0; j < 8; ++j) {
            int r = eros[e + j];
            v[j] = srcq[(size_t)r * 8 + l];
        }
#pragma unroll
        for (int j = 0; j < 8; ++j) {
            a0 += bflo(v[j].x); a1 += bfhi(v[j].x);
            a2 += bflo(v[j].y); a3 += bfhi(v[j].y);
            a4 += bflo(v[j].z); a5 += bfhi(v[j].z);
            a6 += bflo(v[j].w); a7 += bfhi(v[j].w);
        }
    }
    for (; e + 4 <= eend; e += 4) {
        uint4 v[4];
#pragma unroll
        for (int j = 0; j < 4; ++j) {
            int r = eros[e + j];
            v[j] = srcq[(size_t)r * 8 + l];
        }
#pragma unroll
        for (int j = 0; j < 4; ++j) {
            a0 += bflo(v[j].x); a1 += bfhi(v[j].x);
            a2 += bflo(v[j].y); a3 += bfhi(v[j].y);
            a4 += bflo(v[j].z); a5 += bfhi(v[j].z);
            a6 += bflo(v[j].w); a7 += bfhi(v[j].w);
        }
    }
    for (; e < eend; ++e) {
        int r = eros[e];
        uint4 v = srcq[(size_t)r * 8 + l];
        a0 += bflo(v.x); a1 += bfhi(v.x);
        a2 += bflo(v.y); a3 += bfhi(v.y);
        a4 += bflo(v.z); a5 += bfhi(v.z);
        a6 += bflo(v.w); a7 += bfhi(v.w);
    }
    float sc = dinv[node];
    const float4* bp = (const float4*)bias;
    float4 b0 = bp[l * 2], b1 = bp[l * 2 + 1];
    a0 = a0 * sc + b0.x; a1 = a1 * sc + b0.y;
    a2 = a2 * sc + b0.z; a3 = a3 * sc + b0.w;
    a4 = a4 * sc + b1.x; a5 = a5 * sc + b1.y;
    a6 = a6 * sc + b1.z; a7 = a7 * sc + b1.w;
    if (mode) {  // relu + bf16 pack
        a0 = fmaxf(a0, 0.f); a1 = fmaxf(a1, 0.f);
        a2 = fmaxf(a2, 0.f); a3 = fmaxf(a3, 0.f);
        a4 = fmaxf(a4, 0.f); a5 = fmaxf(a5, 0.f);
        a6 = fmaxf(a6, 0.f); a7 = fmaxf(a7, 0.f);
        uint4 o;
        o.x = (unsigned)f2bf(a0) | ((unsigned)f2bf(a1) << 16);
        o.y = (unsigned)f2bf(a2) | ((unsigned)f2bf(a3) << 16);
        o.z = (unsigned)f2bf(a4) | ((unsigned)f2bf(a5) << 16);
        o.w = (unsigned)f2bf(a6) | ((unsigned)f2bf(a7) << 16);
        dstq[(size_t)node * 8 + l] = o;
    } else {
        float4 o0 = make_float4(a0, a1, a2, a3);
        float4 o1 = make_float4(a4, a5, a6, a7);
        float4* d = (float4*)(dstf + (size_t)node * 64 + l * 8);
        d[0] = o0;
        d[1] = o1;
    }
}

extern "C" void kernel_launch(void* const* d_in, const int* in_sizes, int n_in,
                              void* d_out, int out_size, void* d_ws, size_t ws_size,
                              hipStream_t stream) {
    const float* x = (const float*)d_in[0];
    const int* ei = (const int*)d_in[1];  // int32 per harness contract, [2, E]
    const float* W1 = (const float*)d_in[2];
    const float* b1 = (const float*)d_in[3];
    const float* W2 = (const float*)d_in[4];
    const float* b2 = (const float*)d_in[5];

    int N = in_sizes[0] / 128;  // 100000
    int E = in_sizes[1] / 2;    // 1600000
    const int* row = ei;
    const int* col = ei + E;
    int nb = (N + (1 << BKT_SH) - 1) >> BKT_SH;  // 782 buckets

    char* ws = (char*)d_ws;
    int* cursor = (int*)ws;                          // nb ints @ 0
    int* start = (int*)(ws + (1 << 16));             // N ints @ 64 KB
    int* cntarr = (int*)(ws + (1 << 19));            // N ints @ 512 KB
    float* dinv = (float*)(ws + 960 * 1024);         // N floats @ 960 KB
    unsigned* bentries = (unsigned*)(ws + (2 << 20));    // nb*CAP u32 @ 2 MB (12.8 MB)
    unsigned short* Ab = (unsigned short*)(ws + (15 << 20));  // N*64 bf16 @ 15 MB (12.8 MB)
    unsigned short* Hb = (unsigned short*)d_out;     // bf16 h2 scratch in d_out
    float* OUTF = (float*)d_out;                     // final fp32 output

    int gemmblk = (N + BM - 1) / BM;       // 782
    int binblk = (E + CHUNK - 1) / CHUNK;  // 261
    int gblk = (N * 8 + 255) / 256;        // 3125

    // --- CSR build (padded buckets; once, shared by both layers) ---
    k_zero_i<<<(nb + 255) / 256, 256, 0, stream>>>(cursor, nb);
    k_bin<<<binblk, NTB, 0, stream>>>(row, col, cursor, bentries, E);
    k_bucket_sort<<<nb, NTS, 0, stream>>>(bentries, cursor, start, cntarr, dinv, N);

    // Layer 1: Ab = bf16((X@W1)*dinv); Hb = bf16(relu(gather(Ab)*dinv + b1))
    k_gemm_f32in<<<gemmblk, 256, 0, stream>>>(x, W1, dinv, Ab, N, 128);
    k_gather<<<gblk, 256, 0, stream>>>((const uint4*)Ab, (const int*)bentries,
                                       start, cntarr, dinv, b1,
                                       nullptr, (uint4*)Hb, N, 1);

    // Layer 2: Ab = bf16((Hb@W2)*dinv); d_out = gather(Ab)*dinv + b2 (fp32)
    k_gemm_bf16in<<<gemmblk, 256, 0, stream>>>(Hb, W2, dinv, Ab, N, 64);
    k_gather<<<gblk, 256, 0, stream>>>((const uint4*)Ab, (const int*)bentries,
                                       start, cntarr, dinv, b2,
                                       OUTF, nullptr, N, 0);
}